// Round 5
// baseline (490.482 us; speedup 1.0000x reference)
//
#include <hip/hip_runtime.h>

#define NN 100000
#define NE 1600000
#define D 64
#define NB ((NN + 255) / 256)   // 391 scan blocks
#define SCAN2_T 512             // single-block scan width, >= NB

// ---------------------------------------------------------------------------
// K1: degree histogram.  deg[v] = #incoming edges. 1.6M int atomics on a
// 400KB L2-resident array.
// ---------------------------------------------------------------------------
__global__ __launch_bounds__(256) void degree_hist(const int* __restrict__ dst,
                                                   int* __restrict__ deg) {
    for (int i = blockIdx.x * blockDim.x + threadIdx.x; i < NE;
         i += gridDim.x * blockDim.x)
        atomicAdd(&deg[dst[i]], 1);
}

// ---------------------------------------------------------------------------
// K2a: per-block exclusive scan of deg (256/block). partial[i] = exclusive
// scan within block; blockSums[b] = block total.
// ---------------------------------------------------------------------------
__global__ __launch_bounds__(256) void scan1(const int* __restrict__ deg,
                                             int* __restrict__ partial,
                                             int* __restrict__ blockSums) {
    const int t = threadIdx.x;
    const int i = blockIdx.x * 256 + t;
    const int lane = t & 63, wid = t >> 6;
    const int orig = (i < NN) ? deg[i] : 0;
    int v = orig;
#pragma unroll
    for (int off = 1; off < 64; off <<= 1) {
        int n = __shfl_up(v, off, 64);
        if (lane >= off) v += n;
    }
    __shared__ int wsum[4];
    if (lane == 63) wsum[wid] = v;
    __syncthreads();
    if (t == 0) {
        int s = 0;
#pragma unroll
        for (int w = 0; w < 4; ++w) { int tmp = wsum[w]; wsum[w] = s; s += tmp; }
    }
    __syncthreads();
    const int incl = v + wsum[wid];
    if (i < NN) partial[i] = incl - orig;
    if (t == 255) blockSums[blockIdx.x] = incl;
}

// ---------------------------------------------------------------------------
// K2b: single-block exclusive scan of the NB block sums (NB=391 <= 512).
// ---------------------------------------------------------------------------
__global__ __launch_bounds__(SCAN2_T) void scan2(int* __restrict__ blockSums) {
    __shared__ int sm[SCAN2_T];
    const int t = threadIdx.x;
    const int orig = (t < NB) ? blockSums[t] : 0;
    sm[t] = orig;
    __syncthreads();
    for (int off = 1; off < SCAN2_T; off <<= 1) {
        int v = (t >= off) ? sm[t - off] : 0;
        __syncthreads();
        sm[t] += v;
        __syncthreads();
    }
    if (t < NB) blockSums[t] = sm[t] - orig;   // exclusive
}

// ---------------------------------------------------------------------------
// K2c: offs[i] = partial[i] + blockOffset; cursor = copy for bucket fill.
// ---------------------------------------------------------------------------
__global__ __launch_bounds__(256) void scan3(const int* __restrict__ partial,
                                             const int* __restrict__ blockSums,
                                             int* __restrict__ offs,
                                             int* __restrict__ cursor) {
    const int i = blockIdx.x * 256 + threadIdx.x;
    if (i < NN) {
        const int o = partial[i] + blockSums[blockIdx.x];
        offs[i] = o;
        cursor[i] = o;
    }
}

// ---------------------------------------------------------------------------
// K3: bucket fill. csr[offs[dst]..] = src for each edge (order irrelevant:
// addition is commutative). 1.6M int atomics + scattered 4B writes.
// ---------------------------------------------------------------------------
__global__ __launch_bounds__(256) void bucket_fill(const int* __restrict__ src,
                                                   const int* __restrict__ dst,
                                                   int* __restrict__ cursor,
                                                   int* __restrict__ csr) {
    for (int i = blockIdx.x * blockDim.x + threadIdx.x; i < NE;
         i += gridDim.x * blockDim.x) {
        const int pos = atomicAdd(&cursor[dst[i]], 1);
        csr[pos] = src[i];
    }
}

// ---------------------------------------------------------------------------
// K4: fused per-node gather-sum + transform + bias + L2-normalize + colsum.
//   h[v] = normalize((sum_{u in in(v)} x[u]) @ W + b)
// One wave per node; lane j = feature j. Edge indices loaded 64-at-a-time
// coalesced, broadcast via shfl. Gather unrolled 4-wide with independent
// accumulators so 4 x-row loads are in flight per wave (MLP on top of TLP).
// No f32 atomics anywhere.
// ---------------------------------------------------------------------------
__global__ __launch_bounds__(256) void gather_transform_norm(
        const float* __restrict__ x, const int* __restrict__ csr,
        const int* __restrict__ offs, const int* __restrict__ deg,
        const float* __restrict__ W, const float* __restrict__ b,
        float* __restrict__ h, float* __restrict__ colsum) {
    const int lane = threadIdx.x & 63;
    const int wid  = threadIdx.x >> 6;
    float wcol[D];
#pragma unroll
    for (int k = 0; k < D; ++k) wcol[k] = W[k * D + lane];
    const float bj = b[lane];

    const int waveId = (blockIdx.x * blockDim.x + threadIdx.x) >> 6;
    const int nWaves = (gridDim.x * blockDim.x) >> 6;
    float csum = 0.f;
    for (int node = waveId; node < NN; node += nWaves) {
        const int start = offs[node];
        const int cnt   = deg[node];
        float acc0 = 0.f, acc1 = 0.f, acc2 = 0.f, acc3 = 0.f;
        for (int c0 = 0; c0 < cnt; c0 += 64) {
            const int pos  = start + c0 + lane;
            const int idxv = (pos < NE) ? csr[pos] : 0;   // coalesced, guarded
            const int m = (cnt - c0 < 64) ? (cnt - c0) : 64;
            int j = 0;
            for (; j + 3 < m; j += 4) {   // 4 independent gathers in flight
                const int s0 = __shfl(idxv, j,     64);
                const int s1 = __shfl(idxv, j + 1, 64);
                const int s2 = __shfl(idxv, j + 2, 64);
                const int s3 = __shfl(idxv, j + 3, 64);
                acc0 += x[(size_t)s0 * D + lane];
                acc1 += x[(size_t)s1 * D + lane];
                acc2 += x[(size_t)s2 * D + lane];
                acc3 += x[(size_t)s3 * D + lane];
            }
            for (; j < m; ++j) {
                const int s = __shfl(idxv, j, 64);
                acc0 += x[(size_t)s * D + lane];
            }
        }
        const float acc = (acc0 + acc1) + (acc2 + acc3);
        // v[lane] = sum_k acc[k] * W[k][lane] + b[lane]
        float v = bj;
#pragma unroll
        for (int k = 0; k < D; ++k) v = fmaf(__shfl(acc, k, 64), wcol[k], v);
        float ss = v * v;
#pragma unroll
        for (int off = 32; off > 0; off >>= 1) ss += __shfl_xor(ss, off, 64);
        v = v / fmaxf(sqrtf(ss), 1e-12f);
        h[(size_t)node * D + lane] = v;
        csum += v;
    }
    __shared__ float smem[4][64];
    smem[wid][lane] = csum;
    __syncthreads();
    if (wid == 0) {
        const float t = smem[0][lane] + smem[1][lane] + smem[2][lane] + smem[3][lane];
        atomicAdd(&colsum[lane], t);
    }
}

// ---------------------------------------------------------------------------
// K5: logits = dot(colsum/NN, wc) + bc.  One wave.
// ---------------------------------------------------------------------------
__global__ void finalize(const float* __restrict__ colsum,
                         const float* __restrict__ wc,
                         const float* __restrict__ bc,
                         float* __restrict__ out0) {
    const int lane = threadIdx.x;
    float v = colsum[lane] * (1.0f / (float)NN) * wc[lane];
#pragma unroll
    for (int off = 32; off > 0; off >>= 1) v += __shfl_xor(v, off, 64);
    if (lane == 0) out0[0] = v + bc[0];
}

extern "C" void kernel_launch(void* const* d_in, const int* in_sizes, int n_in,
                              void* d_out, int out_size, void* d_ws, size_t ws_size,
                              hipStream_t stream) {
    const float* x   = (const float*)d_in[0];
    const float* W   = (const float*)d_in[1];
    const float* b   = (const float*)d_in[2];
    const float* wc  = (const float*)d_in[3];
    const float* bc  = (const float*)d_in[4];
    const int*   src = (const int*)d_in[5];
    const int*   dst = (const int*)d_in[6];

    float* out = (float*)d_out;        // [0] = logits, [1..] = h (100000 x 64)
    float* h   = out + 1;

    // ws layout (all 4B elems): deg | partial | offs | cursor | blockSums |
    // colsum | csr.  Total ~8.0 MB.
    int*   deg       = (int*)d_ws;
    int*   partial   = deg + NN;
    int*   offs      = partial + NN;
    int*   cursor    = offs + NN;
    int*   blockSums = cursor + NN;
    float* colsum    = (float*)(blockSums + SCAN2_T);
    int*   csr       = (int*)(colsum + 64);

    hipMemsetAsync(deg, 0, NN * sizeof(int), stream);
    hipMemsetAsync(colsum, 0, 64 * sizeof(float), stream);

    degree_hist<<<2048, 256, 0, stream>>>(dst, deg);
    scan1<<<NB, 256, 0, stream>>>(deg, partial, blockSums);
    scan2<<<1, SCAN2_T, 0, stream>>>(blockSums);
    scan3<<<NB, 256, 0, stream>>>(partial, blockSums, offs, cursor);
    bucket_fill<<<2048, 256, 0, stream>>>(src, dst, cursor, csr);
    gather_transform_norm<<<1024, 256, 0, stream>>>(x, csr, offs, deg, W, b, h, colsum);
    finalize<<<1, 64, 0, stream>>>(colsum, wc, bc, out);
}

// Round 7
// 428.020 us; speedup vs baseline: 1.1459x; 1.1459x over previous
//
#include <hip/hip_runtime.h>

#define NN 100000
#define NE 1600000
#define D 64
#define NB ((NN + 255) / 256)   // 391 scan blocks
#define SCAN2_T 512             // single-block scan width, >= NB

// ---------------------------------------------------------------------------
// K1: degree histogram.  deg[v] = #incoming edges. int4-vectorized edge read
// (NE = 400000*4 exactly); 1.6M int atomics on a 400KB L2-resident array.
// ---------------------------------------------------------------------------
__global__ __launch_bounds__(256) void degree_hist(const int* __restrict__ dst,
                                                   int* __restrict__ deg) {
    const int n4 = NE / 4;
    for (int i = blockIdx.x * blockDim.x + threadIdx.x; i < n4;
         i += gridDim.x * blockDim.x) {
        const int4 d = reinterpret_cast<const int4*>(dst)[i];
        atomicAdd(&deg[d.x], 1);
        atomicAdd(&deg[d.y], 1);
        atomicAdd(&deg[d.z], 1);
        atomicAdd(&deg[d.w], 1);
    }
}

// ---------------------------------------------------------------------------
// K2a: per-block exclusive scan of deg (256/block).
// ---------------------------------------------------------------------------
__global__ __launch_bounds__(256) void scan1(const int* __restrict__ deg,
                                             int* __restrict__ partial,
                                             int* __restrict__ blockSums) {
    const int t = threadIdx.x;
    const int i = blockIdx.x * 256 + t;
    const int lane = t & 63, wid = t >> 6;
    const int orig = (i < NN) ? deg[i] : 0;
    int v = orig;
#pragma unroll
    for (int off = 1; off < 64; off <<= 1) {
        int n = __shfl_up(v, off, 64);
        if (lane >= off) v += n;
    }
    __shared__ int wsum[4];
    if (lane == 63) wsum[wid] = v;
    __syncthreads();
    if (t == 0) {
        int s = 0;
#pragma unroll
        for (int w = 0; w < 4; ++w) { int tmp = wsum[w]; wsum[w] = s; s += tmp; }
    }
    __syncthreads();
    const int incl = v + wsum[wid];
    if (i < NN) partial[i] = incl - orig;
    if (t == 255) blockSums[blockIdx.x] = incl;
}

// ---------------------------------------------------------------------------
// K2b: single-block exclusive scan of the NB block sums (NB=391 <= 512).
// ---------------------------------------------------------------------------
__global__ __launch_bounds__(SCAN2_T) void scan2(int* __restrict__ blockSums) {
    __shared__ int sm[SCAN2_T];
    const int t = threadIdx.x;
    const int orig = (t < NB) ? blockSums[t] : 0;
    sm[t] = orig;
    __syncthreads();
    for (int off = 1; off < SCAN2_T; off <<= 1) {
        int v = (t >= off) ? sm[t - off] : 0;
        __syncthreads();
        sm[t] += v;
        __syncthreads();
    }
    if (t < NB) blockSums[t] = sm[t] - orig;   // exclusive
}

// ---------------------------------------------------------------------------
// K2c: offs[i] = partial[i] + blockOffset; cursor copy for bucket fill.
// ---------------------------------------------------------------------------
__global__ __launch_bounds__(256) void scan3(const int* __restrict__ partial,
                                             const int* __restrict__ blockSums,
                                             int* __restrict__ offs,
                                             int* __restrict__ cursor) {
    const int i = blockIdx.x * 256 + threadIdx.x;
    if (i < NN) {
        const int o = partial[i] + blockSums[blockIdx.x];
        offs[i] = o;
        cursor[i] = o;
    }
}

// ---------------------------------------------------------------------------
// K3: bucket fill. csr[offs[dst]..] = src per edge (order irrelevant).
// int4-vectorized index reads; 1.6M int atomics + scattered 4B writes.
// ---------------------------------------------------------------------------
__global__ __launch_bounds__(256) void bucket_fill(const int* __restrict__ src,
                                                   const int* __restrict__ dst,
                                                   int* __restrict__ cursor,
                                                   int* __restrict__ csr) {
    const int n4 = NE / 4;
    for (int i = blockIdx.x * blockDim.x + threadIdx.x; i < n4;
         i += gridDim.x * blockDim.x) {
        const int4 d = reinterpret_cast<const int4*>(dst)[i];
        const int4 s = reinterpret_cast<const int4*>(src)[i];
        csr[atomicAdd(&cursor[d.x], 1)] = s.x;
        csr[atomicAdd(&cursor[d.y], 1)] = s.y;
        csr[atomicAdd(&cursor[d.z], 1)] = s.z;
        csr[atomicAdd(&cursor[d.w], 1)] = s.w;
    }
}

// ---------------------------------------------------------------------------
// K4: fused per-node gather-sum + transform + bias + L2-normalize + colsum.
// Layout: 64 lanes = 4 edge-slots x 16 lanes x float4 (16B/lane), so one
// global_load_dwordx4 fetches FOUR x-rows (1KB/instr); unroll 4 -> up to 16
// edges in flight per wave. W cached in LDS transposed+padded instead of 64
// VGPRs -> lower VGPR count, more resident waves.
// ---------------------------------------------------------------------------
__global__ __launch_bounds__(256) void gather_transform_norm(
        const float* __restrict__ x, const int* __restrict__ csr,
        const int* __restrict__ offs, const int* __restrict__ deg,
        const float* __restrict__ W, const float* __restrict__ b,
        float* __restrict__ h, float* __restrict__ colsum) {
    const int lane = threadIdx.x & 63;
    const int wid  = threadIdx.x >> 6;
    const int grp  = lane >> 4;   // edge slot 0..3
    const int sub  = lane & 15;   // feature slice (features 4*sub..4*sub+3)

    __shared__ float Wt[64 * 65];     // Wt[l*65+k] = W[k][l]
    __shared__ float smem[4][64];
    for (int idx = threadIdx.x; idx < 64 * 64; idx += 256) {
        const int k = idx >> 6, l = idx & 63;
        Wt[l * 65 + k] = W[idx];
    }
    __syncthreads();
    const float bj = b[lane];
    const float* wrow = &Wt[lane * 65];

    const int waveId = (blockIdx.x * blockDim.x + threadIdx.x) >> 6;
    const int nWaves = (gridDim.x * blockDim.x) >> 6;
    float csum = 0.f;
    for (int node = waveId; node < NN; node += nWaves) {
        const int start = offs[node];
        const int cnt   = deg[node];
        float ax = 0.f, ay = 0.f, az = 0.f, aw = 0.f;
        for (int c0 = 0; c0 < cnt; c0 += 64) {
            const int pos  = start + c0 + lane;
            const int idxv = (pos < NE) ? csr[pos] : 0;   // coalesced, guarded
            const int m = (cnt - c0 < 64) ? (cnt - c0) : 64;
#pragma unroll 4
            for (int j = 0; j < m; j += 4) {
                const int e = j + grp;
                const int s = __shfl(idxv, e, 64);        // ds_bpermute
                if (e < m) {
                    const float4 v = *reinterpret_cast<const float4*>(
                        x + (size_t)s * D + 4 * sub);     // 1KB/wave, 4 rows
                    ax += v.x; ay += v.y; az += v.z; aw += v.w;
                }
            }
        }
        // reduce the 4 edge-slots: lanes {l, l+16, l+32, l+48} share a slice
#pragma unroll
        for (int off = 16; off <= 32; off <<= 1) {
            ax += __shfl_xor(ax, off, 64);
            ay += __shfl_xor(ay, off, 64);
            az += __shfl_xor(az, off, 64);
            aw += __shfl_xor(aw, off, 64);
        }
        // transform: v[lane] = b[lane] + sum_k acc[k] * W[k][lane];
        // acc[4*k0+c] lives in lane k0, float4 component c.
        float v = bj;
#pragma unroll
        for (int k0 = 0; k0 < 16; ++k0) {
            const float a0 = __shfl(ax, k0, 64);
            const float a1 = __shfl(ay, k0, 64);
            const float a2 = __shfl(az, k0, 64);
            const float a3 = __shfl(aw, k0, 64);
            v = fmaf(a0, wrow[4 * k0 + 0], v);
            v = fmaf(a1, wrow[4 * k0 + 1], v);
            v = fmaf(a2, wrow[4 * k0 + 2], v);
            v = fmaf(a3, wrow[4 * k0 + 3], v);
        }
        float ss = v * v;
#pragma unroll
        for (int off = 32; off > 0; off >>= 1) ss += __shfl_xor(ss, off, 64);
        v = v / fmaxf(sqrtf(ss), 1e-12f);
        h[(size_t)node * D + lane] = v;
        csum += v;
    }
    smem[wid][lane] = csum;
    __syncthreads();
    if (wid == 0) {
        const float t = smem[0][lane] + smem[1][lane] + smem[2][lane] + smem[3][lane];
        atomicAdd(&colsum[lane], t);
    }
}

// ---------------------------------------------------------------------------
// K5: logits = dot(colsum/NN, wc) + bc.  One wave.
// ---------------------------------------------------------------------------
__global__ void finalize(const float* __restrict__ colsum,
                         const float* __restrict__ wc,
                         const float* __restrict__ bc,
                         float* __restrict__ out0) {
    const int lane = threadIdx.x;
    float v = colsum[lane] * (1.0f / (float)NN) * wc[lane];
#pragma unroll
    for (int off = 32; off > 0; off >>= 1) v += __shfl_xor(v, off, 64);
    if (lane == 0) out0[0] = v + bc[0];
}

extern "C" void kernel_launch(void* const* d_in, const int* in_sizes, int n_in,
                              void* d_out, int out_size, void* d_ws, size_t ws_size,
                              hipStream_t stream) {
    const float* x   = (const float*)d_in[0];
    const float* W   = (const float*)d_in[1];
    const float* b   = (const float*)d_in[2];
    const float* wc  = (const float*)d_in[3];
    const float* bc  = (const float*)d_in[4];
    const int*   src = (const int*)d_in[5];
    const int*   dst = (const int*)d_in[6];

    float* out = (float*)d_out;        // [0] = logits, [1..] = h (100000 x 64)
    float* h   = out + 1;

    // ws layout (4B elems): deg | partial | offs | cursor | blockSums |
    // colsum | csr.  Total ~8.0 MB.
    int*   deg       = (int*)d_ws;
    int*   partial   = deg + NN;
    int*   offs      = partial + NN;
    int*   cursor    = offs + NN;
    int*   blockSums = cursor + NN;
    float* colsum    = (float*)(blockSums + SCAN2_T);
    int*   csr       = (int*)(colsum + 64);

    hipMemsetAsync(deg, 0, NN * sizeof(int), stream);
    hipMemsetAsync(colsum, 0, 64 * sizeof(float), stream);

    degree_hist<<<2048, 256, 0, stream>>>(dst, deg);
    scan1<<<NB, 256, 0, stream>>>(deg, partial, blockSums);
    scan2<<<1, SCAN2_T, 0, stream>>>(blockSums);
    scan3<<<NB, 256, 0, stream>>>(partial, blockSums, offs, cursor);
    bucket_fill<<<2048, 256, 0, stream>>>(src, dst, cursor, csr);
    gather_transform_norm<<<2048, 256, 0, stream>>>(x, csr, offs, deg, W, b, h, colsum);
    finalize<<<1, 64, 0, stream>>>(colsum, wc, bc, out);
}

// Round 8
// 427.586 us; speedup vs baseline: 1.1471x; 1.0010x over previous
//
#include <hip/hip_runtime.h>

#define NN 100000
#define NE 1600000
#define D 64
#define NK 8                      // XCD-privatization classes
#define M (NN * NK)               // 800000 scan items
#define SCAN_BS 1024
#define NBA ((M + SCAN_BS - 1) / SCAN_BS)   // 782 scan blocks

// ---------------------------------------------------------------------------
// K1: XCD-privatized degree histogram. deg8[k][v] = #edges of class k into v,
// class k = (int4-item index & 7) — matches round-robin block->XCD dispatch,
// so each 128B counter line is touched by (mostly) ONE XCD: no cross-XCD
// coherence ping-pong. Any k-partition is correct; correlation = speed only.
// ---------------------------------------------------------------------------
__global__ __launch_bounds__(256) void degree_hist(const int* __restrict__ dst,
                                                   int* __restrict__ deg8) {
    const int n4 = NE / 4;
    for (int i = blockIdx.x * blockDim.x + threadIdx.x; i < n4;
         i += gridDim.x * blockDim.x) {
        const int4 d = reinterpret_cast<const int4*>(dst)[i];
        int* dk = deg8 + (size_t)(i & 7) * NN;
        atomicAdd(&dk[d.x], 1);
        atomicAdd(&dk[d.y], 1);
        atomicAdd(&dk[d.z], 1);
        atomicAdd(&dk[d.w], 1);
    }
}

// ---------------------------------------------------------------------------
// K2a: block-level exclusive scan over M=800K items in (v-major, k-minor)
// order: item i -> (v=i>>3, k=i&7), storage slot k*NN+v. Writes block-local
// exclusive scan into cursor8[slot], block total into bsum.
// ---------------------------------------------------------------------------
__global__ __launch_bounds__(SCAN_BS) void scanA(const int* __restrict__ deg8,
                                                 int* __restrict__ cursor8,
                                                 int* __restrict__ bsum) {
    const int t = threadIdx.x;
    const int i = blockIdx.x * SCAN_BS + t;
    const int lane = t & 63, wid = t >> 6;   // 16 waves
    int orig = 0, slot = 0;
    if (i < M) {
        const int v = i >> 3, k = i & 7;
        slot = k * NN + v;
        orig = deg8[slot];
    }
    int val = orig;
#pragma unroll
    for (int off = 1; off < 64; off <<= 1) {
        int n = __shfl_up(val, off, 64);
        if (lane >= off) val += n;
    }
    __shared__ int wsum[16];
    if (lane == 63) wsum[wid] = val;
    __syncthreads();
    if (t == 0) {
        int s = 0;
#pragma unroll
        for (int w = 0; w < 16; ++w) { int tmp = wsum[w]; wsum[w] = s; s += tmp; }
    }
    __syncthreads();
    const int incl = val + wsum[wid];
    if (i < M) cursor8[slot] = incl - orig;
    if (t == SCAN_BS - 1) bsum[blockIdx.x] = incl;
}

// ---------------------------------------------------------------------------
// K2b: single-block exclusive scan of the NBA block sums (782 <= 1024).
// ---------------------------------------------------------------------------
__global__ __launch_bounds__(SCAN_BS) void scanB(int* __restrict__ bsum) {
    __shared__ int sm[SCAN_BS];
    const int t = threadIdx.x;
    const int orig = (t < NBA) ? bsum[t] : 0;
    sm[t] = orig;
    __syncthreads();
    for (int off = 1; off < SCAN_BS; off <<= 1) {
        int v = (t >= off) ? sm[t - off] : 0;
        __syncthreads();
        sm[t] += v;
        __syncthreads();
    }
    if (t < NBA) bsum[t] = sm[t] - orig;   // exclusive
}

// ---------------------------------------------------------------------------
// K2c: finalize offsets: cursor8[slot] += block offset. Node v's CSR range is
// [offs_node[v], offs_node[v+1]) (its 8 k-sub-segments are contiguous).
// ---------------------------------------------------------------------------
__global__ __launch_bounds__(SCAN_BS) void scanC(int* __restrict__ cursor8,
                                                 const int* __restrict__ bsum,
                                                 int* __restrict__ offs_node) {
    const int i = blockIdx.x * SCAN_BS + threadIdx.x;
    if (i < M) {
        const int v = i >> 3, k = i & 7;
        const int slot = k * NN + v;
        const int o = cursor8[slot] + bsum[blockIdx.x];
        cursor8[slot] = o;
        if (k == 0) offs_node[v] = o;
    }
    if (i == 0) offs_node[NN] = NE;
}

// ---------------------------------------------------------------------------
// K3: bucket fill with XCD-privatized cursors. SAME k = (i & 7) mapping as
// degree_hist (grid-independent), so each class's sub-segment sizes match.
// ---------------------------------------------------------------------------
__global__ __launch_bounds__(256) void bucket_fill(const int* __restrict__ src,
                                                   const int* __restrict__ dst,
                                                   int* __restrict__ cursor8,
                                                   int* __restrict__ csr) {
    const int n4 = NE / 4;
    for (int i = blockIdx.x * blockDim.x + threadIdx.x; i < n4;
         i += gridDim.x * blockDim.x) {
        const int4 d = reinterpret_cast<const int4*>(dst)[i];
        const int4 s = reinterpret_cast<const int4*>(src)[i];
        int* cur = cursor8 + (size_t)(i & 7) * NN;
        csr[atomicAdd(&cur[d.x], 1)] = s.x;
        csr[atomicAdd(&cur[d.y], 1)] = s.y;
        csr[atomicAdd(&cur[d.z], 1)] = s.z;
        csr[atomicAdd(&cur[d.w], 1)] = s.w;
    }
}

// ---------------------------------------------------------------------------
// K4: fused per-node gather-sum + transform + bias + L2-normalize + colsum.
// 64 lanes = 4 edge-slots x 16 lanes x float4: one dwordx4 fetches 4 rows
// (1KB/instr); unroll 4 -> 16 edges in flight/wave. W in LDS (transposed,
// padded). VGPR stays ~60 -> full 32 waves/CU.
// ---------------------------------------------------------------------------
__global__ __launch_bounds__(256) void gather_transform_norm(
        const float* __restrict__ x, const int* __restrict__ csr,
        const int* __restrict__ offs_node,
        const float* __restrict__ W, const float* __restrict__ b,
        float* __restrict__ h, float* __restrict__ colsum) {
    const int lane = threadIdx.x & 63;
    const int wid  = threadIdx.x >> 6;
    const int grp  = lane >> 4;   // edge slot 0..3
    const int sub  = lane & 15;   // feature slice (features 4*sub..4*sub+3)

    __shared__ float Wt[64 * 65];     // Wt[l*65+k] = W[k][l]
    __shared__ float smem[4][64];
    for (int idx = threadIdx.x; idx < 64 * 64; idx += 256) {
        const int k = idx >> 6, l = idx & 63;
        Wt[l * 65 + k] = W[idx];
    }
    __syncthreads();
    const float bj = b[lane];
    const float* wrow = &Wt[lane * 65];

    const int waveId = (blockIdx.x * blockDim.x + threadIdx.x) >> 6;
    const int nWaves = (gridDim.x * blockDim.x) >> 6;
    float csum = 0.f;
    for (int node = waveId; node < NN; node += nWaves) {
        const int start = offs_node[node];
        const int cnt   = offs_node[node + 1] - start;
        float ax = 0.f, ay = 0.f, az = 0.f, aw = 0.f;
        for (int c0 = 0; c0 < cnt; c0 += 64) {
            const int pos  = start + c0 + lane;
            const int idxv = (pos < NE) ? csr[pos] : 0;   // coalesced, guarded
            const int m = (cnt - c0 < 64) ? (cnt - c0) : 64;
#pragma unroll 4
            for (int j = 0; j < m; j += 4) {
                const int e = j + grp;
                const int s = __shfl(idxv, e, 64);        // ds_bpermute
                if (e < m) {
                    const float4 v = *reinterpret_cast<const float4*>(
                        x + (size_t)s * D + 4 * sub);     // 1KB/wave, 4 rows
                    ax += v.x; ay += v.y; az += v.z; aw += v.w;
                }
            }
        }
        // reduce the 4 edge-slots: lanes {l, l+16, l+32, l+48} share a slice
#pragma unroll
        for (int off = 16; off <= 32; off <<= 1) {
            ax += __shfl_xor(ax, off, 64);
            ay += __shfl_xor(ay, off, 64);
            az += __shfl_xor(az, off, 64);
            aw += __shfl_xor(aw, off, 64);
        }
        // transform: v[lane] = b[lane] + sum_k acc[k] * W[k][lane];
        // acc[4*k0+c] lives in lane k0, float4 component c.
        float v = bj;
#pragma unroll
        for (int k0 = 0; k0 < 16; ++k0) {
            const float a0 = __shfl(ax, k0, 64);
            const float a1 = __shfl(ay, k0, 64);
            const float a2 = __shfl(az, k0, 64);
            const float a3 = __shfl(aw, k0, 64);
            v = fmaf(a0, wrow[4 * k0 + 0], v);
            v = fmaf(a1, wrow[4 * k0 + 1], v);
            v = fmaf(a2, wrow[4 * k0 + 2], v);
            v = fmaf(a3, wrow[4 * k0 + 3], v);
        }
        float ss = v * v;
#pragma unroll
        for (int off = 32; off > 0; off >>= 1) ss += __shfl_xor(ss, off, 64);
        v = v / fmaxf(sqrtf(ss), 1e-12f);
        h[(size_t)node * D + lane] = v;
        csum += v;
    }
    smem[wid][lane] = csum;
    __syncthreads();
    if (wid == 0) {
        const float t = smem[0][lane] + smem[1][lane] + smem[2][lane] + smem[3][lane];
        atomicAdd(&colsum[lane], t);
    }
}

// ---------------------------------------------------------------------------
// K5: logits = dot(colsum/NN, wc) + bc.  One wave.
// ---------------------------------------------------------------------------
__global__ void finalize(const float* __restrict__ colsum,
                         const float* __restrict__ wc,
                         const float* __restrict__ bc,
                         float* __restrict__ out0) {
    const int lane = threadIdx.x;
    float v = colsum[lane] * (1.0f / (float)NN) * wc[lane];
#pragma unroll
    for (int off = 32; off > 0; off >>= 1) v += __shfl_xor(v, off, 64);
    if (lane == 0) out0[0] = v + bc[0];
}

extern "C" void kernel_launch(void* const* d_in, const int* in_sizes, int n_in,
                              void* d_out, int out_size, void* d_ws, size_t ws_size,
                              hipStream_t stream) {
    const float* x   = (const float*)d_in[0];
    const float* W   = (const float*)d_in[1];
    const float* b   = (const float*)d_in[2];
    const float* wc  = (const float*)d_in[3];
    const float* bc  = (const float*)d_in[4];
    const int*   src = (const int*)d_in[5];
    const int*   dst = (const int*)d_in[6];

    float* out = (float*)d_out;        // [0] = logits, [1..] = h (100000 x 64)
    float* h   = out + 1;

    // ws layout (4B elems): deg8[M] | cursor8[M] | bsum[1024] |
    // offs_node[NN+1] | colsum[64] | csr[NE].  Total ~13.2 MB.
    int*   deg8      = (int*)d_ws;
    int*   cursor8   = deg8 + M;
    int*   bsum      = cursor8 + M;
    int*   offs_node = bsum + SCAN_BS;
    float* colsum    = (float*)(offs_node + NN + 1);
    int*   csr       = (int*)(colsum + 64);

    hipMemsetAsync(deg8, 0, (size_t)M * sizeof(int), stream);
    hipMemsetAsync(colsum, 0, 64 * sizeof(float), stream);

    degree_hist<<<2048, 256, 0, stream>>>(dst, deg8);
    scanA<<<NBA, SCAN_BS, 0, stream>>>(deg8, cursor8, bsum);
    scanB<<<1, SCAN_BS, 0, stream>>>(bsum);
    scanC<<<NBA, SCAN_BS, 0, stream>>>(cursor8, bsum, offs_node);
    bucket_fill<<<2048, 256, 0, stream>>>(src, dst, cursor8, csr);
    gather_transform_norm<<<4096, 256, 0, stream>>>(x, csr, offs_node, W, b, h, colsum);
    finalize<<<1, 64, 0, stream>>>(colsum, wc, bc, out);
}